// Round 1
// baseline (329.220 us; speedup 1.0000x reference)
//
#include <hip/hip_runtime.h>

// Problem constants (fixed by the reference): B=2, S=2048, D=1024, H=16, d=64.
#define SEQ 2048
#define DM  1024
#define NH  16
#define DH  64

typedef __attribute__((ext_vector_type(8))) __bf16 bf16x8;
typedef __attribute__((ext_vector_type(4))) float f32x4;

// fp32 -> bf16 (round-to-nearest-even)
__device__ inline unsigned short f2b(float f) {
  union { float f; unsigned u; } a; a.f = f;
  unsigned u = a.u;
  u += 0x7fffu + ((u >> 16) & 1u);
  return (unsigned short)(u >> 16);
}

// async global->LDS, 16B per lane; LDS dest = uniform base + lane*16
__device__ inline void glds16(const void* g, void* s) {
  __builtin_amdgcn_global_load_lds((const __attribute__((address_space(1))) void*)g,
                                   (__attribute__((address_space(3))) void*)s,
                                   16, 0, 0);
}

__global__ __launch_bounds__(256) void cvt_kernel(const float* __restrict__ src,
                                                  unsigned short* __restrict__ dst,
                                                  int n4) {
  int i = blockIdx.x * 256 + threadIdx.x;
  if (i >= n4) return;
  float4 v = ((const float4*)src)[i];
  ushort4 o;
  o.x = f2b(v.x); o.y = f2b(v.y); o.z = f2b(v.z); o.w = f2b(v.w);
  ((ushort4*)dst)[i] = o;
}

// C[M,N] = A[M,K] @ Bt[N,K]^T, bf16 inputs, 128x128 tile, 4 waves (2x2 of 64x64),
// 16x16x32 bf16 MFMA. A,Bt row-major with K contiguous (lda=ldb=K), ldc=N.
template<bool F32OUT>
__device__ inline void gemm_body(const unsigned short* __restrict__ A,
                                 const unsigned short* __restrict__ Bt,
                                 void* __restrict__ Cv, int N, int K) {
  __shared__ unsigned short As[128 * 64];  // [row][k], 64 bf16 per row, no pad (glds)
  __shared__ unsigned short Bs[128 * 64];
  const int tid = threadIdx.x;
  const int wave = tid >> 6, lane = tid & 63;
  const int quad = lane >> 4, l16 = lane & 15;
  const int m0 = blockIdx.y * 128, n0 = blockIdx.x * 128;
  const int wm = (wave >> 1) * 64, wn = (wave & 1) * 64;
  const int srow = lane >> 3, scol = (lane & 7) * 8;

  f32x4 acc[4][4];
#pragma unroll
  for (int i = 0; i < 4; i++)
#pragma unroll
    for (int j = 0; j < 4; j++) acc[i][j] = (f32x4)0.f;

  for (int k0 = 0; k0 < K; k0 += 64) {
#pragma unroll
    for (int c = 0; c < 4; c++) {
      int inst = wave * 4 + c;       // 16 insts cover 128 rows x 64 k
      int row = inst * 8 + srow;
      glds16(A + (size_t)(m0 + row) * K + k0 + scol, &As[inst * 512]);
      glds16(Bt + (size_t)(n0 + row) * K + k0 + scol, &Bs[inst * 512]);
    }
    __syncthreads();
#pragma unroll
    for (int ks = 0; ks < 2; ks++) {
      bf16x8 af[4], bfr[4];
#pragma unroll
      for (int i = 0; i < 4; i++)
        af[i] = *(const bf16x8*)&As[(wm + i * 16 + l16) * 64 + ks * 32 + quad * 8];
#pragma unroll
      for (int j = 0; j < 4; j++)
        bfr[j] = *(const bf16x8*)&Bs[(wn + j * 16 + l16) * 64 + ks * 32 + quad * 8];
#pragma unroll
      for (int i = 0; i < 4; i++)
#pragma unroll
        for (int j = 0; j < 4; j++)
          acc[i][j] = __builtin_amdgcn_mfma_f32_16x16x32_bf16(af[i], bfr[j],
                                                              acc[i][j], 0, 0, 0);
    }
    __syncthreads();
  }
  // C/D layout: col = lane&15, row = quad*4 + reg (m89/m91 verified)
#pragma unroll
  for (int i = 0; i < 4; i++)
#pragma unroll
    for (int j = 0; j < 4; j++)
#pragma unroll
      for (int r = 0; r < 4; r++) {
        int row = m0 + wm + i * 16 + quad * 4 + r;
        int col = n0 + wn + j * 16 + l16;
        if (F32OUT)
          ((float*)Cv)[(size_t)row * N + col] = acc[i][j][r];
        else
          ((unsigned short*)Cv)[(size_t)row * N + col] = f2b(acc[i][j][r]);
      }
}

__global__ __launch_bounds__(256) void gemm_qkv(
    const unsigned short* __restrict__ A0, const unsigned short* __restrict__ A1,
    const unsigned short* __restrict__ A2, const unsigned short* __restrict__ B0,
    const unsigned short* __restrict__ B1, const unsigned short* __restrict__ B2,
    unsigned short* __restrict__ C0, unsigned short* __restrict__ C1,
    unsigned short* __restrict__ C2) {
  const unsigned short* A = blockIdx.z == 0 ? A0 : blockIdx.z == 1 ? A1 : A2;
  const unsigned short* Bt = blockIdx.z == 0 ? B0 : blockIdx.z == 1 ? B1 : B2;
  unsigned short* C = blockIdx.z == 0 ? C0 : blockIdx.z == 1 ? C1 : C2;
  gemm_body<false>(A, Bt, (void*)C, DM, DM);
}

__global__ __launch_bounds__(256) void gemm_out(const unsigned short* __restrict__ A,
                                                const unsigned short* __restrict__ Bt,
                                                float* __restrict__ C) {
  gemm_body<true>(A, Bt, (void*)C, DM, DM);
}

// Flash attention. Grid: (B*H, S/64). Block: 256 (4 waves); wave w owns q rows
// [Q0+16w, Q0+16w+16). Scores computed transposed (S^T = K·Q^T) so softmax'd P
// matches the PV A-operand layout after a per-wave LDS round-trip.
__global__ __launch_bounds__(256) void attn_kernel(const unsigned short* __restrict__ Qp,
                                                   const unsigned short* __restrict__ Kp,
                                                   const unsigned short* __restrict__ Vp,
                                                   const int* __restrict__ sen_len,
                                                   unsigned short* __restrict__ ctx) {
  __shared__ unsigned short Ks[64 * 64];     // [j][d]
  __shared__ unsigned short Vt[64 * 64];     // [d][j] (transposed)
  __shared__ unsigned short Pl[4][16 * 64];  // per-wave P: [q][j]

  const int tid = threadIdx.x;
  const int wave = tid >> 6, lane = tid & 63;
  const int quad = lane >> 4, l16 = lane & 15;
  const int bh = blockIdx.x;
  const int b = bh >> 4, h = bh & 15;
  const int Q0 = blockIdx.y * 64;
  const int slen = sen_len[b];

  const int qrow = Q0 + wave * 16 + l16;  // this lane's q-row for softmax stats
  // Q as B-operand: B[k=d][n=q] -> lane holds Q[q=l16][d=quad*8.. (+32 for second)]
  const size_t qbase = ((size_t)b * SEQ + qrow) * DM + h * DH;
  bf16x8 qf0 = *(const bf16x8*)(Qp + qbase + quad * 8);
  bf16x8 qf1 = *(const bf16x8*)(Qp + qbase + 32 + quad * 8);

  float m = -1e30f, l = 0.f;
  f32x4 o[4];
#pragma unroll
  for (int i = 0; i < 4; i++) o[i] = (f32x4)0.f;

  const int jend = (Q0 + 64 < slen) ? (Q0 + 64) : slen;  // block-uniform
  const int srow = lane >> 3, scol = (lane & 7) * 8;

  for (int j0 = 0; j0 < jend; j0 += 64) {
    // stage K chunk [j0, j0+64) rows, row-major
#pragma unroll
    for (int c = 0; c < 2; c++) {
      int inst = wave * 2 + c;
      int j = inst * 8 + srow;
      glds16(Kp + ((size_t)b * SEQ + j0 + j) * DM + h * DH + scol, &Ks[inst * 512]);
    }
    // stage V chunk transposed: Vt[d][j]
#pragma unroll
    for (int c = 0; c < 2; c++) {
      int idx = c * 256 + tid;
      int j = idx >> 3, d0 = (idx & 7) * 8;
      uint4 vv = *(const uint4*)(Vp + ((size_t)b * SEQ + j0 + j) * DM + h * DH + d0);
      const unsigned short* pv = (const unsigned short*)&vv;
#pragma unroll
      for (int e = 0; e < 8; e++) Vt[(d0 + e) * 64 + j] = pv[e];
    }
    __syncthreads();

    // S^T tiles: D[m=key][n=q]; lane holds key = kt*16 + quad*4 + r, q = l16
    f32x4 sacc[4];
#pragma unroll
    for (int kt = 0; kt < 4; kt++) sacc[kt] = (f32x4)0.f;
#pragma unroll
    for (int kt = 0; kt < 4; kt++) {
      bf16x8 a0 = *(const bf16x8*)&Ks[(kt * 16 + l16) * 64 + quad * 8];
      bf16x8 a1 = *(const bf16x8*)&Ks[(kt * 16 + l16) * 64 + 32 + quad * 8];
      sacc[kt] = __builtin_amdgcn_mfma_f32_16x16x32_bf16(a0, qf0, sacc[kt], 0, 0, 0);
      sacc[kt] = __builtin_amdgcn_mfma_f32_16x16x32_bf16(a1, qf1, sacc[kt], 0, 0, 0);
    }
    // scale + mask + per-lane max over 16 keys
    float s[4][4];
    float cmax = -1e30f;
#pragma unroll
    for (int kt = 0; kt < 4; kt++)
#pragma unroll
      for (int r = 0; r < 4; r++) {
        int j = j0 + kt * 16 + quad * 4 + r;
        float v = (j <= qrow && j < slen) ? sacc[kt][r] * 0.125f : -1e30f;
        s[kt][r] = v;
        cmax = fmaxf(cmax, v);
      }
    // row (q) reduction across the 4 quads holding the same q = l16
    cmax = fmaxf(cmax, __shfl_xor(cmax, 16));
    cmax = fmaxf(cmax, __shfl_xor(cmax, 32));
    float mnew = fmaxf(m, cmax);
    float alpha = __expf(m - mnew);
    float psum = 0.f;
#pragma unroll
    for (int kt = 0; kt < 4; kt++)
#pragma unroll
      for (int r = 0; r < 4; r++) {
        float p = __expf(s[kt][r] - mnew);
        psum += p;
        Pl[wave][l16 * 64 + kt * 16 + quad * 4 + r] = f2b(p);
      }
    psum += __shfl_xor(psum, 16);
    psum += __shfl_xor(psum, 32);
    l = l * alpha + psum;
    m = mnew;
    // rescale ctx accumulators; ctx C-layout row q = quad*4 + r lives in lane
    // (q) of quad 0, so broadcast alpha from srcLane = quad*4 + r
#pragma unroll
    for (int r = 0; r < 4; r++) {
      float ar = __shfl(alpha, quad * 4 + r);
#pragma unroll
      for (int ni = 0; ni < 4; ni++) o[ni][r] *= ar;
    }
    // PV: D[m=q][n=d] += P[q][j] V[j][d], two K=32 steps over the 64-key chunk
#pragma unroll
    for (int ko = 0; ko < 2; ko++) {
      bf16x8 pf = *(const bf16x8*)&Pl[wave][l16 * 64 + ko * 32 + quad * 8];
#pragma unroll
      for (int ni = 0; ni < 4; ni++) {
        bf16x8 vf = *(const bf16x8*)&Vt[(ni * 16 + l16) * 64 + ko * 32 + quad * 8];
        o[ni] = __builtin_amdgcn_mfma_f32_16x16x32_bf16(pf, vf, o[ni], 0, 0, 0);
      }
    }
    __syncthreads();
  }

  // epilogue: normalize by l (per ctx-row q = quad*4 + r) and store bf16 ctx
#pragma unroll
  for (int r = 0; r < 4; r++) {
    float lr = __shfl(l, quad * 4 + r);
    float inv = 1.0f / lr;
    int row = Q0 + wave * 16 + quad * 4 + r;
#pragma unroll
    for (int ni = 0; ni < 4; ni++) {
      float v = o[ni][r] * inv;
      ctx[((size_t)b * SEQ + row) * DM + h * DH + ni * 16 + l16] = f2b(v);
    }
  }
}

// residual add + LayerNorm, one row (1024 floats) per block
__global__ __launch_bounds__(256) void ln_kernel(const float* __restrict__ xp,
                                                 const float* __restrict__ resid,
                                                 const float* __restrict__ gamma,
                                                 const float* __restrict__ beta,
                                                 float* __restrict__ out) {
  const int row = blockIdx.x;
  const int tid = threadIdx.x;
  const size_t base = (size_t)row * DM + tid * 4;
  float4 x = *(const float4*)(xp + base);
  float4 rv = *(const float4*)(resid + base);
  x.x += rv.x; x.y += rv.y; x.z += rv.z; x.w += rv.w;
  float s = x.x + x.y + x.z + x.w;
  float s2 = x.x * x.x + x.y * x.y + x.z * x.z + x.w * x.w;
#pragma unroll
  for (int off = 1; off < 64; off <<= 1) {
    s += __shfl_xor(s, off);
    s2 += __shfl_xor(s2, off);
  }
  __shared__ float sm[4], sm2[4];
  const int wave = tid >> 6, lane = tid & 63;
  if (lane == 0) { sm[wave] = s; sm2[wave] = s2; }
  __syncthreads();
  s = sm[0] + sm[1] + sm[2] + sm[3];
  s2 = sm2[0] + sm2[1] + sm2[2] + sm2[3];
  float mean = s * (1.f / 1024.f);
  float var = s2 * (1.f / 1024.f) - mean * mean;
  float rstd = rsqrtf(var + 1e-6f);
  float4 g = *(const float4*)(gamma + tid * 4);
  float4 bt = *(const float4*)(beta + tid * 4);
  float4 o;
  o.x = (x.x - mean) * rstd * g.x + bt.x;
  o.y = (x.y - mean) * rstd * g.y + bt.y;
  o.z = (x.z - mean) * rstd * g.z + bt.z;
  o.w = (x.w - mean) * rstd * g.w + bt.w;
  *(float4*)(out + base) = o;
}

extern "C" void kernel_launch(void* const* d_in, const int* in_sizes, int n_in,
                              void* d_out, int out_size, void* d_ws, size_t ws_size,
                              hipStream_t stream) {
  const float* q     = (const float*)d_in[0];
  const float* k     = (const float*)d_in[1];
  const float* v     = (const float*)d_in[2];
  const float* Wq    = (const float*)d_in[3];
  const float* Wk    = (const float*)d_in[4];
  const float* Wv    = (const float*)d_in[5];
  const float* Wo    = (const float*)d_in[6];
  const float* gamma = (const float*)d_in[7];
  const float* beta  = (const float*)d_in[8];
  const int* sen_len = (const int*)d_in[9];
  float* out = (float*)d_out;

  char* ws = (char*)d_ws;
  const size_t MB = (size_t)1 << 20;
  if (ws_size < 64 * MB) return;  // need 64MB of scratch
  unsigned short* qb  = (unsigned short*)(ws + 0 * MB);
  unsigned short* kb  = (unsigned short*)(ws + 8 * MB);
  unsigned short* vb  = (unsigned short*)(ws + 16 * MB);
  unsigned short* Wqb = (unsigned short*)(ws + 24 * MB);
  unsigned short* Wkb = (unsigned short*)(ws + 26 * MB);
  unsigned short* Wvb = (unsigned short*)(ws + 28 * MB);
  unsigned short* Wob = (unsigned short*)(ws + 30 * MB);
  unsigned short* Qp  = (unsigned short*)(ws + 32 * MB);
  unsigned short* Kp  = (unsigned short*)(ws + 40 * MB);
  unsigned short* Vp  = (unsigned short*)(ws + 48 * MB);
  unsigned short* ctx = (unsigned short*)(ws + 56 * MB);
  float* outp = (float*)(ws + 0 * MB);  // 16MB, reuses qb+kb (dead by then)

  // 1) fp32 -> bf16
  cvt_kernel<<<4096, 256, 0, stream>>>(q, qb, 1048576);
  cvt_kernel<<<4096, 256, 0, stream>>>(k, kb, 1048576);
  cvt_kernel<<<4096, 256, 0, stream>>>(v, vb, 1048576);
  cvt_kernel<<<1024, 256, 0, stream>>>(Wq, Wqb, 262144);
  cvt_kernel<<<1024, 256, 0, stream>>>(Wk, Wkb, 262144);
  cvt_kernel<<<1024, 256, 0, stream>>>(Wv, Wvb, 262144);
  cvt_kernel<<<1024, 256, 0, stream>>>(Wo, Wob, 262144);

  // 2) Q/K/V projections (y = x @ W^T), fused via grid.z
  gemm_qkv<<<dim3(8, 32, 3), 256, 0, stream>>>(qb, kb, vb, Wqb, Wkb, Wvb, Qp, Kp, Vp);

  // 3) flash attention
  attn_kernel<<<dim3(32, 32), 256, 0, stream>>>(Qp, Kp, Vp, sen_len, ctx);

  // 4) output projection (fp32 out)
  gemm_out<<<dim3(8, 32), 256, 0, stream>>>(ctx, Wob, outp);

  // 5) residual + LayerNorm
  ln_kernel<<<4096, 256, 0, stream>>>(outp, q, gamma, beta, out);
}